// Round 5
// baseline (95.662 us; speedup 1.0000x reference)
//
#include <hip/hip_runtime.h>
#include <math.h>

#define NG 9
#define NBI 16             // i-chunks: 512 raw rows each -> NS=2 exact, no variance
#define NBJ 64             // j-chunks: 128 raw rows each (~64 non-toxic)
#define NBLK (NBI * NBJ)   // 1024 blocks = 4/CU
#define NS 2               // register i-slots (raw rows, neutral-padded)
#define JCAP 256           // LDS j-list capacity (JRAW<=256 for B<=16384)
#define LOG2E 1.4426950408889634f
#define LN2   0.6931471805599453f
// part rows: 0..26 sums | 27..35 cT[g] | 36 nI | 37..45 cN[g] | 46 nJ
#define ROWS 47

// Dispatch 1. Key change vs round 4: NO i-side classify/compaction.
// i-rows load straight into registers; non-toxic/invalid slots get
// li=+1e30 (log2-domain softplus -> exactly 0) and mi=0 (excluded from all
// fold buckets). j-side keeps single-pass ballot-compaction into LDS.
// All ROWS partial slots are written unconditionally (no memset needed).
__global__ __launch_bounds__(256, 4) void k_main(
    const float* __restrict__ logits, const float* __restrict__ ytox,
    const float* __restrict__ yid, int B, float* __restrict__ part) {

    __shared__ float2 jS[JCAP];
    __shared__ int   swcnt[4], swoff[4], sbase;
    __shared__ int   scT[4][NG], scN[4][NG], scI[4];
    __shared__ float red[4][27];
    __shared__ float acc[27];

    const int tid = threadIdx.x, lane = tid & 63, wave = tid >> 6;
    const int blk = blockIdx.x;
    const int bi = blk & (NBI - 1), bj = blk >> 4;
    const int IRAW = (B + NBI - 1) / NBI;
    const int JRAW = (B + NBJ - 1) / NBJ;
    const unsigned long long lt = (1ull << lane) - 1ull;

    if (tid < 4 * NG) { scT[tid / NG][tid % NG] = 0; scN[tid / NG][tid % NG] = 0; }
    if (tid < 4) scI[tid] = 0;
    if (tid == 0) sbase = 0;
    if (tid < 27) acc[tid] = 0.f;
    __syncthreads();

    // ---- classify + compact this block's j-chunk (non-toxic) into LDS ----
    const int jbase0 = bj * JRAW;
    for (int r0 = 0; r0 < JRAW; r0 += 256) {
        const int row = jbase0 + r0 + tid;
        const bool valid = (r0 + tid < JRAW) && (row < B);
        float l = 0.f; bool nt = false; int m = 0;
        if (valid) {
            l = logits[row] * LOG2E;          // log2-domain softplus
            nt = ytox[row] < 0.5f;
#pragma unroll
            for (int g = 0; g < NG; ++g)
                if (yid[row * NG + g] >= 0.5f) m |= 1 << g;
        }
        const unsigned long long bal = __ballot(nt);
        const int pos = __popcll(bal & lt);
        if (lane == 0) swcnt[wave] = __popcll(bal);
#pragma unroll
        for (int g = 0; g < NG; ++g) {
            const unsigned long long bg = __ballot(nt && ((m >> g) & 1));
            if (lane == 0) scN[wave][g] += __popcll(bg);
        }
        __syncthreads();
        if (tid == 0) {
            int b = sbase;
#pragma unroll
            for (int w = 0; w < 4; ++w) { swoff[w] = b; b += swcnt[w]; }
            sbase = b;
        }
        __syncthreads();
        if (nt) jS[swoff[wave] + pos] = make_float2(l, __int_as_float(m));
    }
    __syncthreads();
    const int nJloc = sbase;

    // ---- i rows straight to registers (neutral-padded), then pair loop ----
    const int ibase0 = bi * IRAW;
    const int islots = (IRAW + 255) >> 8;
    const int ngroups = (islots + NS - 1) / NS;   // 1 at B=8192

    for (int grp = 0; grp < ngroups; ++grp) {
        float li[NS]; int mi[NS]; float Ra[NS]; float Rg[NS][NG];
#pragma unroll
        for (int u = 0; u < NS; ++u) {
            const int k = (grp * NS + u) * 256 + tid;
            const int row = ibase0 + k;
            const bool valid = (k < IRAW) && (row < B);
            float l = 0.f; bool tox = false; int m = 0;
            if (valid) {
                l = logits[row] * LOG2E;
                tox = ytox[row] >= 0.5f;
#pragma unroll
                for (int g = 0; g < NG; ++g)
                    if (yid[row * NG + g] >= 0.5f) m |= 1 << g;
            }
            li[u] = tox ? l : 1e30f;      // pad: exp2(lj-1e30) = 0 -> s = 0 exactly
            mi[u] = tox ? m : 0;
            Ra[u] = 0.f;
#pragma unroll
            for (int g = 0; g < NG; ++g) Rg[u][g] = 0.f;
            if (bj == 0) {                // owner blocks compute i-side counts
                const unsigned long long bt = __ballot(tox);
                if (lane == 0) scI[wave] += __popcll(bt);
#pragma unroll
                for (int g = 0; g < NG; ++g) {
                    const unsigned long long bg = __ballot(tox && ((m >> g) & 1));
                    if (lane == 0) scT[wave][g] += __popcll(bg);
                }
            }
        }

#pragma unroll 4
        for (int k = 0; k < nJloc; ++k) {
            const float2 jv = jS[k];                                   // b64 broadcast
            const float lj = jv.x;
            const int mj = __builtin_amdgcn_readfirstlane(__float_as_int(jv.y));
            float s[NS];
#pragma unroll
            for (int u = 0; u < NS; ++u) {
                s[u] = __builtin_amdgcn_logf(1.f + __builtin_amdgcn_exp2f(lj - li[u]));
                Ra[u] += s[u];
            }
#pragma unroll
            for (int g = 0; g < NG; ++g) {
                const float bg = ((mj >> g) & 1) ? 1.f : 0.f;           // scalar cselect
#pragma unroll
                for (int u = 0; u < NS; ++u) Rg[u][g] = fmaf(bg, s[u], Rg[u][g]);
            }
        }

        // fold NS slots x 9 groups into 27 block sums
#pragma unroll
        for (int g = 0; g < NG; ++g) {
            float x0 = 0.f, x1 = 0.f, x2 = 0.f;
#pragma unroll
            for (int u = 0; u < NS; ++u) {
                const bool ing = (mi[u] >> g) & 1;
                x0 += ing ? Rg[u][g] : 0.f;
                x1 += ing ? 0.f : Rg[u][g];          // only toxic i have Rg != 0
                x2 += ing ? (Ra[u] - Rg[u][g]) : 0.f;
            }
#pragma unroll
            for (int off = 32; off > 0; off >>= 1) {
                x0 += __shfl_xor(x0, off, 64);
                x1 += __shfl_xor(x1, off, 64);
                x2 += __shfl_xor(x2, off, 64);
            }
            if (lane == 0) {
                red[wave][g] = x0; red[wave][NG + g] = x1; red[wave][2 * NG + g] = x2;
            }
        }
        __syncthreads();
        if (tid < 27) acc[tid] += red[0][tid] + red[1][tid] + red[2][tid] + red[3][tid];
        __syncthreads();   // protect red before next group's overwrite
    }

    // ---- publish partials + counts (plain stores; every row written) ----
    if (tid < 27) part[tid * NBLK + blk] = acc[tid];
    if (tid >= 32 && tid < 32 + NG) {        // rows 27..35: cT (owner: bj==0)
        const int g = tid - 32;
        part[(27 + g) * NBLK + blk] = (bj == 0)
            ? (float)(scT[0][g] + scT[1][g] + scT[2][g] + scT[3][g]) : 0.f;
    }
    if (tid == 41) part[36 * NBLK + blk] = (bj == 0)
        ? (float)(scI[0] + scI[1] + scI[2] + scI[3]) : 0.f;
    if (tid >= 64 && tid < 64 + NG) {        // rows 37..45: cN (owner: bi==0)
        const int g = tid - 64;
        part[(37 + g) * NBLK + blk] = (bi == 0)
            ? (float)(scN[0][g] + scN[1][g] + scN[2][g] + scN[3][g]) : 0.f;
    }
    if (tid == 73) part[46 * NBLK + blk] = (bi == 0) ? (float)nJloc : 0.f;
}

// Dispatch 2: one block (8 waves) reduces ROWS x NBLK partials + fp64 epilogue.
__global__ __launch_bounds__(512) void k_final(
    const float* __restrict__ part, float* __restrict__ out) {
    __shared__ float fin[27];
    __shared__ float finC[20];
    const int tid = threadIdx.x, lane = tid & 63, wave = tid >> 6;

    for (int r = wave; r < 27; r += 8) {                 // sum rows (x ln2)
        float s = 0.f;
#pragma unroll
        for (int q = 0; q < NBLK / 64; ++q) s += part[r * NBLK + (q << 6) + lane];
#pragma unroll
        for (int off = 32; off > 0; off >>= 1) s += __shfl_xor(s, off, 64);
        if (lane == 0) fin[r] = s * LN2;
    }
    for (int r = 27 + wave; r < ROWS; r += 8) {          // count rows
        float s = 0.f;
#pragma unroll
        for (int q = 0; q < NBLK / 64; ++q) s += part[r * NBLK + (q << 6) + lane];
#pragma unroll
        for (int off = 32; off > 0; off >>= 1) s += __shfl_xor(s, off, 64);
        if (lane == 0) finC[r - 27] = s;
    }
    __syncthreads();
    if (tid == 0) {
        const long long nT64 = (long long)(finC[9] + 0.5f);
        const long long nN64 = (long long)(finC[19] + 0.5f);
        double accd = 0.0; int ngv = 0;
        for (int g = 0; g < NG; ++g) {
            const long long cT = (long long)(finC[g] + 0.5f);
            const long long cN = (long long)(finC[10 + g] + 0.5f);
            const long long c0 = cT * cN;
            const long long c1 = (nT64 - cT) * cN;
            const long long c2 = cT * (nN64 - cN);
            const double t0 = (double)fin[g]          / (double)(c0 > 0 ? c0 : 1);
            const double t1 = (double)fin[NG + g]     / (double)(c1 > 0 ? c1 : 1);
            const double t2 = (double)fin[2 * NG + g] / (double)(c2 > 0 ? c2 : 1);
            const int nv = (c0 > 0) + (c1 > 0) + (c2 > 0);
            const double gl = ((c0 > 0 ? t0 : 0.0) + (c1 > 0 ? t1 : 0.0) +
                               (c2 > 0 ? t2 : 0.0)) / (double)(nv > 0 ? nv : 1);
            if (nv > 0) { const double g2 = gl * gl; accd += g2 * g2; ++ngv; }
        }
        const double mp = accd / (double)(ngv > 0 ? ngv : 1);
        const double loss = sqrt(sqrt(mp));   // ^(1/4)
        out[0] = (float)(ngv > 0 ? loss : 0.0);
    }
}

extern "C" void kernel_launch(void* const* d_in, const int* in_sizes, int n_in,
                              void* d_out, int out_size, void* d_ws, size_t ws_size,
                              hipStream_t stream) {
    const float* logits = (const float*)d_in[0];
    const float* ytox   = (const float*)d_in[1];
    const float* yid    = (const float*)d_in[2];
    const int B = in_sizes[0];
    float* part = (float*)d_ws;   // ROWS x NBLK floats = 188 KB, no zeroing needed

    k_main<<<dim3(NBLK), dim3(256), 0, stream>>>(logits, ytox, yid, B, part);
    k_final<<<dim3(1), dim3(512), 0, stream>>>(part, (float*)d_out);
}

// Round 6
// 91.862 us; speedup vs baseline: 1.0414x; 1.0414x over previous
//
#include <hip/hip_runtime.h>
#include <math.h>

#define NG 9
#define NBLK 1024          // pair blocks: 4/CU
#define CHROWS 256         // classification chunk rows (= block size)
#define NCHMAX 256         // supports B <= 65536
#define JT 32              // j-tile width (nbI*nbJ = 8*128 = 1024 at B=8192)
#define ITILE 512          // i-fragment: 2 slots x 256 threads
#define LOG2E 1.4426950408889634f
#define LN2   0.6931471805599453f

// ---------------------------------------------------------------------------
// Dispatch 1: classify ALL rows exactly once. Each of nCh blocks compacts its
// 256-row chunk into deterministic per-chunk segments (iTmp/jTmp at c*CHROWS)
// and plain-stores its counts. No atomics, no memset, no inter-block traffic.
// ---------------------------------------------------------------------------
__global__ __launch_bounds__(256) void k_classify(
    const float* __restrict__ logits, const float* __restrict__ ytox,
    const float* __restrict__ yid, int B,
    int* __restrict__ cntT, int* __restrict__ cntN,
    int* __restrict__ gTc, int* __restrict__ gNc,
    float2* __restrict__ iTmp, float2* __restrict__ jTmp) {

    __shared__ int wT[4], wN[4], oT[4], oN[4];
    __shared__ int gT[4][NG], gN[4][NG];

    const int tid = threadIdx.x, lane = tid & 63, wave = tid >> 6;
    const int c = blockIdx.x;
    const int row = c * CHROWS + tid;
    const bool v = row < B;

    float l = 0.f; bool tox = false, non = false; int m = 0;
    if (v) {
        l = logits[row] * LOG2E;          // pre-scale: softplus in log2 domain
        tox = ytox[row] >= 0.5f;
        non = !tox;
#pragma unroll
        for (int g = 0; g < NG; ++g)
            if (yid[row * NG + g] >= 0.5f) m |= 1 << g;
    }
    const unsigned long long bTox = __ballot(tox), bNon = __ballot(non);
    const unsigned long long lt = (1ull << lane) - 1ull;
    const int pT = __popcll(bTox & lt), pN = __popcll(bNon & lt);
    if (lane == 0) { wT[wave] = __popcll(bTox); wN[wave] = __popcll(bNon); }
#pragma unroll
    for (int g = 0; g < NG; ++g) {
        const unsigned long long bt = __ballot(tox && ((m >> g) & 1));
        const unsigned long long bn = __ballot(non && ((m >> g) & 1));
        if (lane == 0) { gT[wave][g] = __popcll(bt); gN[wave][g] = __popcll(bn); }
    }
    __syncthreads();
    if (tid == 0) {
        int a = 0, b = 0;
#pragma unroll
        for (int w = 0; w < 4; ++w) { oT[w] = a; a += wT[w]; oN[w] = b; b += wN[w]; }
        cntT[c] = a; cntN[c] = b;
    }
    __syncthreads();
    if (tox) iTmp[c * CHROWS + oT[wave] + pT] = make_float2(l, __int_as_float(m));
    if (non) jTmp[c * CHROWS + oN[wave] + pN] = make_float2(l, __int_as_float(m));
    if (tid < NG)
        gTc[c * NG + tid] = gT[0][tid] + gT[1][tid] + gT[2][tid] + gT[3][tid];
    else if (tid >= 64 && tid < 64 + NG) {
        const int g = tid - 64;
        gNc[c * NG + g] = gN[0][g] + gN[1][g] + gN[2][g] + gN[3][g];
    }
}

// ---------------------------------------------------------------------------
// Dispatch 2: pair kernel. Each block rebuilds the chunk-prefix table in LDS
// (nCh+1 entries), reads ragged lists via binary search (verified in R2),
// runs the register-tiled pair loop, writes 27 partials unconditionally.
// ---------------------------------------------------------------------------
__global__ __launch_bounds__(256, 4) void k_pairs(
    const int* __restrict__ cntT, const int* __restrict__ cntN,
    const float2* __restrict__ iTmp, const float2* __restrict__ jTmp,
    int B, float* __restrict__ part) {

    __shared__ int offT[NCHMAX + 1], offN[NCHMAX + 1];
    __shared__ float2 jS[JT];
    __shared__ float red[4][27];
    __shared__ float acc[27];

    const int tid = threadIdx.x, lane = tid & 63, wave = tid >> 6;
    const int blk = blockIdx.x;
    const int nCh = (B + CHROWS - 1) / CHROWS;

    for (int c = tid; c < nCh; c += 256) { offT[c + 1] = cntT[c]; offN[c + 1] = cntN[c]; }
    if (tid == 0) { offT[0] = 0; offN[0] = 0; }
    __syncthreads();
    if (tid == 0)
        for (int c = 0; c < nCh; ++c) { offT[c + 1] += offT[c]; offN[c + 1] += offN[c]; }
    if (tid < 27) acc[tid] = 0.f;
    __syncthreads();
    const int nI = offT[nCh], nJ = offN[nCh];

    auto findChunk = [&](const int* off, int k) {     // dense idx -> chunk
        int lo = 0, hi = nCh;
        while (hi - lo > 1) { const int mid = (lo + hi) >> 1; if (off[mid] <= k) lo = mid; else hi = mid; }
        return lo;
    };

    float li0 = 1e30f, li1 = 1e30f;   // sentinel: exp2(-inf)=0 -> contributes 0
    int mi0 = 0, mi1 = 0;
    float Ra0 = 0.f, Ra1 = 0.f;
    float Rg0[NG], Rg1[NG];
#pragma unroll
    for (int g = 0; g < NG; ++g) { Rg0[g] = 0.f; Rg1[g] = 0.f; }

    auto flush = [&]() {   // fold 2 i-slots x 9 groups into the 27 block sums
#pragma unroll
        for (int g = 0; g < NG; ++g) {
            const bool i0 = (mi0 >> g) & 1, i1 = (mi1 >> g) & 1;
            float x0 = (i0 ? Rg0[g] : 0.f) + (i1 ? Rg1[g] : 0.f);
            float x1 = (i0 ? 0.f : Rg0[g]) + (i1 ? 0.f : Rg1[g]);
            float x2 = (i0 ? (Ra0 - Rg0[g]) : 0.f) + (i1 ? (Ra1 - Rg1[g]) : 0.f);
#pragma unroll
            for (int off = 32; off > 0; off >>= 1) {
                x0 += __shfl_xor(x0, off, 64);
                x1 += __shfl_xor(x1, off, 64);
                x2 += __shfl_xor(x2, off, 64);
            }
            if (lane == 0) {
                red[wave][g] = x0; red[wave][NG + g] = x1; red[wave][2 * NG + g] = x2;
            }
        }
        __syncthreads();
        if (tid < 27)
            acc[tid] += red[0][tid] + red[1][tid] + red[2][tid] + red[3][tid];
    };

    const int nbI = (nI + ITILE - 1) / ITILE;
    const int nbJ = (nJ + JT - 1) / JT;
    const int nT = nbI * nbJ;

    int prev_bi = -1;
    for (int t = blk; t < nT; t += NBLK) {
        const int bi = t % nbI, bj = t / nbI;   // j-major: bi stable per block
        if (bi != prev_bi) {
            if (prev_bi >= 0) flush();
            const int k0 = bi * ITILE + tid, k1 = k0 + 256;
            float2 a0 = make_float2(1e30f, 0.f), a1 = make_float2(1e30f, 0.f);
            if (k0 < nI) { const int c = findChunk(offT, k0); a0 = iTmp[c * CHROWS + (k0 - offT[c])]; }
            if (k1 < nI) { const int c = findChunk(offT, k1); a1 = iTmp[c * CHROWS + (k1 - offT[c])]; }
            li0 = a0.x; mi0 = __float_as_int(a0.y);
            li1 = a1.x; mi1 = __float_as_int(a1.y);
            Ra0 = 0.f; Ra1 = 0.f;
#pragma unroll
            for (int g = 0; g < NG; ++g) { Rg0[g] = 0.f; Rg1[g] = 0.f; }
            prev_bi = bi;
        }
        const int jbeg = bj * JT;
        const int jcnt = min(JT, nJ - jbeg);
        __syncthreads();                         // jS reuse + red/acc ordering
        if (tid < jcnt) {
            const int k = jbeg + tid;
            const int c = findChunk(offN, k);
            jS[tid] = jTmp[c * CHROWS + (k - offN[c])];
        }
        __syncthreads();
#pragma unroll 4
        for (int k = 0; k < jcnt; ++k) {
            const float2 jv = jS[k];                                  // b64 broadcast
            const float lj = jv.x;
            const int mj = __builtin_amdgcn_readfirstlane(__float_as_int(jv.y));
            // softplus in log2 domain: log2(1 + 2^(lj-li)); *ln2 deferred
            const float s0 = __builtin_amdgcn_logf(1.f + __builtin_amdgcn_exp2f(lj - li0));
            const float s1 = __builtin_amdgcn_logf(1.f + __builtin_amdgcn_exp2f(lj - li1));
            Ra0 += s0; Ra1 += s1;
#pragma unroll
            for (int g = 0; g < NG; ++g) {
                const float bg = ((mj >> g) & 1) ? 1.f : 0.f;          // SGPR select
                Rg0[g] = fmaf(bg, s0, Rg0[g]);
                Rg1[g] = fmaf(bg, s1, Rg1[g]);
            }
        }
    }
    if (prev_bi >= 0) flush();
    if (tid < 27) part[tid * NBLK + blk] = acc[tid];   // zeros when no tiles
}

// ---------------------------------------------------------------------------
// Dispatch 3: reduce 27 x NBLK partials (x ln2) + integer counts + fp64 tail.
// ---------------------------------------------------------------------------
__global__ __launch_bounds__(512) void k_final(
    const float* __restrict__ part, const int* __restrict__ cntT,
    const int* __restrict__ cntN, const int* __restrict__ gTc,
    const int* __restrict__ gNc, int B, float* __restrict__ out) {

    __shared__ float fin[27];
    __shared__ int cTs[NG], cNs[NG], nTs, nNs;
    const int tid = threadIdx.x, lane = tid & 63, wave = tid >> 6;
    const int nCh = (B + CHROWS - 1) / CHROWS;

    for (int r = wave; r < 27; r += 8) {
        float s = 0.f;
#pragma unroll
        for (int q = 0; q < NBLK / 64; ++q) s += part[r * NBLK + (q << 6) + lane];
#pragma unroll
        for (int off = 32; off > 0; off >>= 1) s += __shfl_xor(s, off, 64);
        if (lane == 0) fin[r] = s * LN2;     // undo log2-domain accumulation
    }
    if (tid < NG) {
        int s = 0;
        for (int c = 0; c < nCh; ++c) s += gTc[c * NG + tid];
        cTs[tid] = s;
    } else if (tid >= 64 && tid < 64 + NG) {
        const int g = tid - 64;
        int s = 0;
        for (int c = 0; c < nCh; ++c) s += gNc[c * NG + g];
        cNs[g] = s;
    } else if (tid == 128) {
        int s = 0;
        for (int c = 0; c < nCh; ++c) s += cntT[c];
        nTs = s;
    } else if (tid == 192) {
        int s = 0;
        for (int c = 0; c < nCh; ++c) s += cntN[c];
        nNs = s;
    }
    __syncthreads();
    if (tid == 0) {
        const long long nT64 = nTs, nN64 = nNs;
        double accd = 0.0; int ngv = 0;
        for (int g = 0; g < NG; ++g) {
            const long long cT = cTs[g], cN = cNs[g];
            const long long c0 = cT * cN;
            const long long c1 = (nT64 - cT) * cN;
            const long long c2 = cT * (nN64 - cN);
            const double t0 = (double)fin[g]          / (double)(c0 > 0 ? c0 : 1);
            const double t1 = (double)fin[NG + g]     / (double)(c1 > 0 ? c1 : 1);
            const double t2 = (double)fin[2 * NG + g] / (double)(c2 > 0 ? c2 : 1);
            const int nv = (c0 > 0) + (c1 > 0) + (c2 > 0);
            const double gl = ((c0 > 0 ? t0 : 0.0) + (c1 > 0 ? t1 : 0.0) +
                               (c2 > 0 ? t2 : 0.0)) / (double)(nv > 0 ? nv : 1);
            if (nv > 0) { const double g2 = gl * gl; accd += g2 * g2; ++ngv; }
        }
        const double mp = accd / (double)(ngv > 0 ? ngv : 1);
        const double loss = sqrt(sqrt(mp));   // ^(1/4)
        out[0] = (float)(ngv > 0 ? loss : 0.0);
    }
}

extern "C" void kernel_launch(void* const* d_in, const int* in_sizes, int n_in,
                              void* d_out, int out_size, void* d_ws, size_t ws_size,
                              hipStream_t stream) {
    const float* logits = (const float*)d_in[0];
    const float* ytox   = (const float*)d_in[1];
    const float* yid    = (const float*)d_in[2];
    const int B = in_sizes[0];
    const int nCh = (B + CHROWS - 1) / CHROWS;

    char* ws = (char*)d_ws;
    int* cntT = (int*)ws;                               // NCHMAX ints
    int* cntN = cntT + NCHMAX;                          // NCHMAX
    int* gTc  = cntN + NCHMAX;                          // NCHMAX*NG
    int* gNc  = gTc + NCHMAX * NG;                      // NCHMAX*NG
    float2* iTmp = (float2*)(gNc + NCHMAX * NG);        // B float2 (8B aligned)
    float2* jTmp = iTmp + B;                            // B float2
    float*  part = (float*)(jTmp + B);                  // 27*NBLK floats

    k_classify<<<dim3(nCh), dim3(256), 0, stream>>>(logits, ytox, yid, B,
                                                    cntT, cntN, gTc, gNc, iTmp, jTmp);
    k_pairs<<<dim3(NBLK), dim3(256), 0, stream>>>(cntT, cntN, iTmp, jTmp, B, part);
    k_final<<<dim3(1), dim3(512), 0, stream>>>(part, cntT, cntN, gTc, gNc, B,
                                               (float*)d_out);
}

// Round 7
// 85.568 us; speedup vs baseline: 1.1180x; 1.0736x over previous
//
#include <hip/hip_runtime.h>
#include <math.h>

#define NG 9
#define NBLK 1024          // pair blocks: 4/CU
#define JT 32              // j-tile width (nbI*nbJ = 8*128 = 1024 at B=8192)
#define ITILE 512          // i-fragment: 2 slots x 256 threads (packed as float2)
#define LOG2E 1.4426950408889634f
#define LN2   0.6931471805599453f

typedef float f32x2 __attribute__((ext_vector_type(2)));

// ---------------------------------------------------------------------------
// Dispatch 2: classify once, atomic-reserve dense segments (R1 structure).
// cnts: [0]=nI, [1]=nJ, [2..10]=cT[g], [11..19]=cN[g]   (zeroed by 80B memset)
// ---------------------------------------------------------------------------
__global__ __launch_bounds__(256) void k_classify(
    const float* __restrict__ logits, const float* __restrict__ ytox,
    const float* __restrict__ yid, int B, int* __restrict__ cnts,
    float2* __restrict__ iLM, float2* __restrict__ jLM) {

    __shared__ int wT[4], wN[4], offT[4], offN[4], bT, bN;
    __shared__ int gT[4][NG], gN[4][NG];

    const int tid = threadIdx.x, lane = tid & 63, wave = tid >> 6;
    const int row = blockIdx.x * 256 + tid;
    const bool v = row < B;

    float l = 0.f; bool tox = false, non = false; int m = 0;
    if (v) {
        l = logits[row] * LOG2E;          // pre-scale: softplus in log2 domain
        tox = ytox[row] >= 0.5f;
        non = !tox;
#pragma unroll
        for (int g = 0; g < NG; ++g)
            if (yid[row * NG + g] >= 0.5f) m |= 1 << g;
    }
    const unsigned long long bTox = __ballot(tox), bNon = __ballot(non);
    const unsigned long long lt = (1ull << lane) - 1ull;
    const int pT = __popcll(bTox & lt), pN = __popcll(bNon & lt);
    if (lane == 0) { wT[wave] = __popcll(bTox); wN[wave] = __popcll(bNon); }
#pragma unroll
    for (int g = 0; g < NG; ++g) {
        const unsigned long long bt = __ballot(tox && ((m >> g) & 1));
        const unsigned long long bn = __ballot(non && ((m >> g) & 1));
        if (lane == 0) { gT[wave][g] = __popcll(bt); gN[wave][g] = __popcll(bn); }
    }
    __syncthreads();
    if (tid == 0) {
        int a = 0, b = 0;
#pragma unroll
        for (int w = 0; w < 4; ++w) { offT[w] = a; a += wT[w]; offN[w] = b; b += wN[w]; }
        bT = atomicAdd(&cnts[0], a);
        bN = atomicAdd(&cnts[1], b);
    }
    __syncthreads();
    if (tox) iLM[bT + offT[wave] + pT] = make_float2(l, __int_as_float(m));
    if (non) jLM[bN + offN[wave] + pN] = make_float2(l, __int_as_float(m));
    if (tid < NG)
        atomicAdd(&cnts[2 + tid], gT[0][tid] + gT[1][tid] + gT[2][tid] + gT[3][tid]);
    else if (tid >= 64 && tid < 64 + NG) {
        const int g = tid - 64;
        atomicAdd(&cnts[11 + g], gN[0][g] + gN[1][g] + gN[2][g] + gN[3][g]);
    }
}

// ---------------------------------------------------------------------------
// Dispatch 3: pair kernel over globally-dense lists — no prefix, no search.
// Two i-slots per thread packed into f32x2 lanes; inner loop uses packed
// FP32 (v_pk_sub/add/fma) -> ~12 VALU + 4 trans issues per j per thread.
// ---------------------------------------------------------------------------
__global__ __launch_bounds__(256, 4) void k_pairs(
    const int* __restrict__ cnts, const float2* __restrict__ iLM,
    const float2* __restrict__ jLM, float* __restrict__ part) {

    __shared__ float2 jS[JT];
    __shared__ float red[4][27];
    __shared__ float acc[27];

    const int tid = threadIdx.x, lane = tid & 63, wave = tid >> 6;
    const int blk = blockIdx.x;
    const int nI = cnts[0], nJ = cnts[1];
    const int nbI = (nI + ITILE - 1) / ITILE;
    const int nbJ = (nJ + JT - 1) / JT;
    const int nT = nbI * nbJ;

    if (tid < 27) acc[tid] = 0.f;

    f32x2 li = {1e30f, 1e30f};        // sentinel: exp2(-inf)=0 -> contributes 0
    int mi0 = 0, mi1 = 0;
    f32x2 Ra = {0.f, 0.f};
    f32x2 Rg[NG];
#pragma unroll
    for (int g = 0; g < NG; ++g) Rg[g] = (f32x2){0.f, 0.f};

    auto flush = [&]() {   // fold 2 packed slots x 9 groups into 27 block sums
#pragma unroll
        for (int g = 0; g < NG; ++g) {
            const bool i0 = (mi0 >> g) & 1, i1 = (mi1 >> g) & 1;
            const float r0 = Rg[g].x, r1 = Rg[g].y;
            float x0 = (i0 ? r0 : 0.f) + (i1 ? r1 : 0.f);
            float x1 = (i0 ? 0.f : r0) + (i1 ? 0.f : r1);
            float x2 = (i0 ? (Ra.x - r0) : 0.f) + (i1 ? (Ra.y - r1) : 0.f);
#pragma unroll
            for (int off = 32; off > 0; off >>= 1) {
                x0 += __shfl_xor(x0, off, 64);
                x1 += __shfl_xor(x1, off, 64);
                x2 += __shfl_xor(x2, off, 64);
            }
            if (lane == 0) {
                red[wave][g] = x0; red[wave][NG + g] = x1; red[wave][2 * NG + g] = x2;
            }
        }
        __syncthreads();
        if (tid < 27)
            acc[tid] += red[0][tid] + red[1][tid] + red[2][tid] + red[3][tid];
    };

    int prev_bi = -1;
    for (int t = blk; t < nT; t += NBLK) {
        const int bi = t % nbI, bj = t / nbI;   // j-major: bi stable per block
        if (bi != prev_bi) {
            if (prev_bi >= 0) flush();
            const int k0 = bi * ITILE + tid, k1 = k0 + 256;
            const float2 a0 = (k0 < nI) ? iLM[k0] : make_float2(1e30f, 0.f);
            const float2 a1 = (k1 < nI) ? iLM[k1] : make_float2(1e30f, 0.f);
            li.x = a0.x; mi0 = __float_as_int(a0.y);
            li.y = a1.x; mi1 = __float_as_int(a1.y);
            Ra = (f32x2){0.f, 0.f};
#pragma unroll
            for (int g = 0; g < NG; ++g) Rg[g] = (f32x2){0.f, 0.f};
            prev_bi = bi;
        }
        const int jbeg = bj * JT;
        const int jcnt = min(JT, nJ - jbeg);
        __syncthreads();                         // jS reuse + red/acc ordering
        if (tid < jcnt) jS[tid] = jLM[jbeg + tid];
        __syncthreads();
#pragma unroll 2
        for (int k = 0; k < jcnt; ++k) {
            const float2 jv = jS[k];                                  // b64 broadcast
            const int mj = __builtin_amdgcn_readfirstlane(__float_as_int(jv.y));
            const f32x2 ljv = {jv.x, jv.x};
            const f32x2 d = ljv - li;                                 // v_pk_sub? (2->1)
            f32x2 e;
            e.x = __builtin_amdgcn_exp2f(d.x);                        // trans x2
            e.y = __builtin_amdgcn_exp2f(d.y);
            const f32x2 one = {1.f, 1.f};
            const f32x2 tpe = e + one;                                // v_pk_add
            f32x2 s;
            s.x = __builtin_amdgcn_logf(tpe.x);                       // trans x2
            s.y = __builtin_amdgcn_logf(tpe.y);
            Ra = Ra + s;                                              // v_pk_add
#pragma unroll
            for (int g = 0; g < NG; ++g) {
                const float bg = ((mj >> g) & 1) ? 1.f : 0.f;          // SGPR select
                const f32x2 bgv = {bg, bg};
                Rg[g] = __builtin_elementwise_fma(bgv, s, Rg[g]);      // v_pk_fma
            }
        }
    }
    if (prev_bi >= 0) flush();
    if (tid < 27) part[tid * NBLK + blk] = acc[tid];   // zeros when no tiles
}

// ---------------------------------------------------------------------------
// Dispatch 4: reduce 27 x NBLK partials (x ln2) + integer counts + fp64 tail.
// ---------------------------------------------------------------------------
__global__ __launch_bounds__(512) void k_final(
    const float* __restrict__ part, const int* __restrict__ cnts,
    float* __restrict__ out) {
    __shared__ float fin[27];
    const int tid = threadIdx.x, lane = tid & 63, wave = tid >> 6;
    for (int r = wave; r < 27; r += 8) {
        float s = 0.f;
#pragma unroll
        for (int q = 0; q < NBLK / 64; ++q) s += part[r * NBLK + (q << 6) + lane];
#pragma unroll
        for (int off = 32; off > 0; off >>= 1) s += __shfl_xor(s, off, 64);
        if (lane == 0) fin[r] = s * LN2;     // undo log2-domain accumulation
    }
    __syncthreads();
    if (tid == 0) {
        const long long nT64 = cnts[0], nN64 = cnts[1];
        double accd = 0.0; int ngv = 0;
        for (int g = 0; g < NG; ++g) {
            const long long cT = cnts[2 + g], cN = cnts[11 + g];
            const long long c0 = cT * cN;
            const long long c1 = (nT64 - cT) * cN;
            const long long c2 = cT * (nN64 - cN);
            const double t0 = (double)fin[g]          / (double)(c0 > 0 ? c0 : 1);
            const double t1 = (double)fin[NG + g]     / (double)(c1 > 0 ? c1 : 1);
            const double t2 = (double)fin[2 * NG + g] / (double)(c2 > 0 ? c2 : 1);
            const int nv = (c0 > 0) + (c1 > 0) + (c2 > 0);
            const double gl = ((c0 > 0 ? t0 : 0.0) + (c1 > 0 ? t1 : 0.0) +
                               (c2 > 0 ? t2 : 0.0)) / (double)(nv > 0 ? nv : 1);
            if (nv > 0) { const double g2 = gl * gl; accd += g2 * g2; ++ngv; }
        }
        const double mp = accd / (double)(ngv > 0 ? ngv : 1);
        const double loss = sqrt(sqrt(mp));  // ^(1/4)
        out[0] = (float)(ngv > 0 ? loss : 0.0);
    }
}

extern "C" void kernel_launch(void* const* d_in, const int* in_sizes, int n_in,
                              void* d_out, int out_size, void* d_ws, size_t ws_size,
                              hipStream_t stream) {
    const float* logits = (const float*)d_in[0];
    const float* ytox   = (const float*)d_in[1];
    const float* yid    = (const float*)d_in[2];
    const int B = in_sizes[0];

    char* ws = (char*)d_ws;
    int*    cnts = (int*)ws;                      // 20 ints (pad to 128B)
    float2* iLM  = (float2*)(ws + 128);           // B float2
    float2* jLM  = iLM + B;                       // B float2
    float*  part = (float*)(jLM + B);             // 27*NBLK floats

    hipMemsetAsync(cnts, 0, 20 * sizeof(int), stream);
    k_classify<<<dim3((B + 255) / 256), dim3(256), 0, stream>>>(
        logits, ytox, yid, B, cnts, iLM, jLM);
    k_pairs<<<dim3(NBLK), dim3(256), 0, stream>>>(cnts, iLM, jLM, part);
    k_final<<<dim3(1), dim3(512), 0, stream>>>(part, cnts, (float*)d_out);
}